// Round 2
// 261.305 us; speedup vs baseline: 1.0149x; 1.0149x over previous
//
#include <hip/hip_runtime.h>
#include <math.h>

#define EPSREG 1e-5f

typedef float vf4 __attribute__((ext_vector_type(4)));   // clang-native float4

// ---------------------------------------------------------------------------
// Per-channel 4x4 Cholesky + triangular inverse + fold affine.
// st[0..3] = sums, st[4..13] = upper-tri products. Writes pp[0..23]:
//   pp[0..15] = M = W_c @ Linv_c (row-major), pp[16..19] = mean, pp[20..23] = bias
// ---------------------------------------------------------------------------
__device__ __forceinline__ void solve_one(const float st[14], float inv_n,
                                          const float* __restrict__ weight,
                                          const float* __restrict__ bias,
                                          int c, float* __restrict__ pp) {
    float m0 = st[0]*inv_n, m1 = st[1]*inv_n, m2 = st[2]*inv_n, m3 = st[3]*inv_n;
    float c00 = st[4]*inv_n  - m0*m0 + EPSREG;
    float c01 = st[5]*inv_n  - m0*m1;
    float c02 = st[6]*inv_n  - m0*m2;
    float c03 = st[7]*inv_n  - m0*m3;
    float c11 = st[8]*inv_n  - m1*m1 + EPSREG;
    float c12 = st[9]*inv_n  - m1*m2;
    float c13 = st[10]*inv_n - m1*m3;
    float c22 = st[11]*inv_n - m2*m2 + EPSREG;
    float c23 = st[12]*inv_n - m2*m3;
    float c33 = st[13]*inv_n - m3*m3 + EPSREG;

    // Cholesky (lower)
    float l00 = sqrtf(c00);
    float l10 = c01 / l00, l20 = c02 / l00, l30 = c03 / l00;
    float l11 = sqrtf(c11 - l10*l10);
    float l21 = (c12 - l20*l10) / l11;
    float l31 = (c13 - l30*l10) / l11;
    float l22 = sqrtf(c22 - l20*l20 - l21*l21);
    float l32 = (c23 - l30*l20 - l31*l21) / l22;
    float l33 = sqrtf(c33 - l30*l30 - l31*l31 - l32*l32);

    // Inverse of lower triangular (forward substitution)
    float i00 = 1.f / l00, i11 = 1.f / l11, i22 = 1.f / l22, i33 = 1.f / l33;
    float i10 = -i11 * (l10 * i00);
    float i20 = -i22 * (l20 * i00 + l21 * i10);
    float i21 = -i22 * (l21 * i11);
    float i30 = -i33 * (l30 * i00 + l31 * i10 + l32 * i20);
    float i31 = -i33 * (l31 * i11 + l32 * i21);
    float i32 = -i33 * (l32 * i22);

    float Li[4][4] = {{i00, 0.f, 0.f, 0.f},
                      {i10, i11, 0.f, 0.f},
                      {i20, i21, i22, 0.f},
                      {i30, i31, i32, i33}};

    #pragma unroll
    for (int i = 0; i < 4; ++i) {
        float w0 = weight[(i*4 + 0)*64 + c];
        float w1 = weight[(i*4 + 1)*64 + c];
        float w2 = weight[(i*4 + 2)*64 + c];
        float w3 = weight[(i*4 + 3)*64 + c];
        #pragma unroll
        for (int j = 0; j < 4; ++j) {
            pp[i*4 + j] = w0*Li[0][j] + w1*Li[1][j] + w2*Li[2][j] + w3*Li[3][j];
        }
    }
    pp[16] = m0; pp[17] = m1; pp[18] = m2; pp[19] = m3;
    pp[20] = bias[0*64 + c];
    pp[21] = bias[1*64 + c];
    pp[22] = bias[2*64 + c];
    pp[23] = bias[3*64 + c];
}

// ---------------------------------------------------------------------------
// Kernel 1: per-channel sufficient statistics.
// x viewed as vf4[npos*64]: element (pos, c) at index pos*64 + c.
// Thread owns channel c = tid&63; (block, lane=tid>>6) owns a contiguous
// slice of positions. 8 independent loads per iteration for latency hiding.
// 1024 blocks = 4 blocks/CU.
// ---------------------------------------------------------------------------
__global__ __launch_bounds__(256) void stats_kernel(const vf4* __restrict__ x,
                                                    float* __restrict__ stats,
                                                    int pos_per_slice) {
    int tid  = threadIdx.x;
    int c    = tid & 63;
    int lane = tid >> 6;                     // 0..3
    int s    = blockIdx.x * 4 + lane;        // slice id

    const vf4* xp = x + (size_t)s * pos_per_slice * 64 + c;

    float a0=0.f,a1=0.f,a2=0.f,a3=0.f;
    float p00=0.f,p01=0.f,p02=0.f,p03=0.f;
    float p11=0.f,p12=0.f,p13=0.f;
    float p22=0.f,p23=0.f,p33=0.f;

    for (int it = 0; it < pos_per_slice; it += 8) {
        vf4 v[8];
        #pragma unroll
        for (int u = 0; u < 8; ++u) v[u] = xp[(it + u) * 64];   // 8 loads in flight
        #pragma unroll
        for (int u = 0; u < 8; ++u) {
            float x0 = v[u].x, x1 = v[u].y, x2 = v[u].z, x3 = v[u].w;
            a0 += x0; a1 += x1; a2 += x2; a3 += x3;
            p00 += x0*x0; p01 += x0*x1; p02 += x0*x2; p03 += x0*x3;
            p11 += x1*x1; p12 += x1*x2; p13 += x1*x3;
            p22 += x2*x2; p23 += x2*x3;
            p33 += x3*x3;
        }
    }

    __shared__ float sm[14 * 256];
    float vals[14] = {a0,a1,a2,a3,p00,p01,p02,p03,p11,p12,p13,p22,p23,p33};
    #pragma unroll
    for (int k = 0; k < 14; ++k) sm[k * 256 + tid] = vals[k];
    __syncthreads();

    if (tid < 64) {
        #pragma unroll
        for (int k = 0; k < 14; ++k) {
            float v = sm[k*256 + tid] + sm[k*256 + 64 + tid]
                    + sm[k*256 + 128 + tid] + sm[k*256 + 192 + tid];
            atomicAdd(&stats[k * 64 + tid], v);
        }
    }
}

// ---------------------------------------------------------------------------
// Kernel 2: fused solve + apply.
// Prologue: threads 0..63 redundantly (per block) compute the per-channel
// 4x4 solve from global stats into LDS (~60 VALU ops each; stats/weight/bias
// are L2-resident -> negligible vs the streaming loop). Removes the separate
// 1-wave solve dispatch and the params global round-trip.
// Main loop: grid-stride, stride % 64 == 0 so channel is thread-invariant;
// 4 independent loads per iteration; nontemporal stores keep the output
// stream from evicting x (L3-resident after kernel 1) on its second read.
// ---------------------------------------------------------------------------
__global__ __launch_bounds__(256) void apply_kernel(const vf4* __restrict__ x,
                                                    vf4* __restrict__ out,
                                                    const float* __restrict__ stats,
                                                    const float* __restrict__ weight,
                                                    const float* __restrict__ bias,
                                                    int total4, float inv_n) {
    __shared__ float sp[64 * 25];

    int tid = threadIdx.x;
    int c   = tid & 63;

    if (tid < 64) {
        float st[14];
        #pragma unroll
        for (int k = 0; k < 14; ++k) st[k] = stats[k*64 + tid];
        solve_one(st, inv_n, weight, bias, tid, &sp[tid * 25]);
    }
    __syncthreads();

    const float* pp = &sp[c * 25];
    float M[16];
    #pragma unroll
    for (int k = 0; k < 16; ++k) M[k] = pp[k];
    float m0 = pp[16], m1 = pp[17], m2 = pp[18], m3 = pp[19];
    float b0 = pp[20], b1 = pp[21], b2 = pp[22], b3 = pp[23];

    int tid0   = blockIdx.x * blockDim.x + tid;
    int stride = gridDim.x * blockDim.x;      // multiple of 64 by launch config
    int i = tid0;
    for (; i + 3 * stride < total4; i += 4 * stride) {
        vf4 v[4];
        #pragma unroll
        for (int u = 0; u < 4; ++u) v[u] = x[i + u * stride];   // 4 loads in flight
        #pragma unroll
        for (int u = 0; u < 4; ++u) {
            float x0 = v[u].x - m0, x1 = v[u].y - m1, x2 = v[u].z - m2, x3 = v[u].w - m3;
            vf4 o;
            o.x = M[0]*x0  + M[1]*x1  + M[2]*x2  + M[3]*x3  + b0;
            o.y = M[4]*x0  + M[5]*x1  + M[6]*x2  + M[7]*x3  + b1;
            o.z = M[8]*x0  + M[9]*x1  + M[10]*x2 + M[11]*x3 + b2;
            o.w = M[12]*x0 + M[13]*x1 + M[14]*x2 + M[15]*x3 + b3;
            __builtin_nontemporal_store(o, &out[i + u * stride]);
        }
    }
    for (; i < total4; i += stride) {
        vf4 v = x[i];
        float x0 = v.x - m0, x1 = v.y - m1, x2 = v.z - m2, x3 = v.w - m3;
        vf4 o;
        o.x = M[0]*x0  + M[1]*x1  + M[2]*x2  + M[3]*x3  + b0;
        o.y = M[4]*x0  + M[5]*x1  + M[6]*x2  + M[7]*x3  + b1;
        o.z = M[8]*x0  + M[9]*x1  + M[10]*x2 + M[11]*x3 + b2;
        o.w = M[12]*x0 + M[13]*x1 + M[14]*x2 + M[15]*x3 + b3;
        __builtin_nontemporal_store(o, &out[i]);
    }
}

extern "C" void kernel_launch(void* const* d_in, const int* in_sizes, int n_in,
                              void* d_out, int out_size, void* d_ws, size_t ws_size,
                              hipStream_t stream) {
    const float* x      = (const float*)d_in[0];   // (32,64,64,64,4) fp32
    const float* weight = (const float*)d_in[1];   // (4,4,64)
    const float* bias   = (const float*)d_in[2];   // (4,64)
    float* out = (float*)d_out;

    float* stats = (float*)d_ws;                   // 14*64 floats

    int n_elem = in_sizes[0];        // 33554432
    int npos   = n_elem / 256;       // 131072 spatial positions
    int total4 = n_elem / 4;         // 8388608 float4 elements
    float inv_n = 1.0f / (float)npos;

    (void)hipMemsetAsync(stats, 0, 14 * 64 * sizeof(float), stream);

    // 1024 blocks * 4 lanes = 4096 slices; 131072/4096 = 32 positions/slice
    int pos_per_slice = npos / 4096;
    stats_kernel<<<1024, 256, 0, stream>>>((const vf4*)x, stats, pos_per_slice);
    apply_kernel<<<2048, 256, 0, stream>>>((const vf4*)x, (vf4*)out, stats,
                                           weight, bias, total4, inv_n);
}